// Round 7
// baseline (309.673 us; speedup 1.0000x reference)
//
#include <hip/hip_runtime.h>
#include <hip/hip_bf16.h>
#include <stdint.h>

// ---------------------------------------------------------------------------
// Fused MHA: QKV GEMMs (fp32-A fused cvt, bf16 MFMA, vectorized head-major
// epilogues) -> causal flash attention (KVBLK=128, swapped 32x32 MFMA,
// in-register softmax) -> output GEMM (128x64 tiles, fp32 out).
// ---------------------------------------------------------------------------

typedef __bf16 bf16;
typedef __bf16 bf16x2v __attribute__((ext_vector_type(2)));
typedef __bf16 bf16x4v __attribute__((ext_vector_type(4)));
typedef __bf16 bf16x8v __attribute__((ext_vector_type(8)));
typedef float  f32x4v  __attribute__((ext_vector_type(4)));
typedef float  f32x16v __attribute__((ext_vector_type(16)));
typedef unsigned int uint32x2v __attribute__((ext_vector_type(2)));

#define MFMA32(a, b, c) __builtin_amdgcn_mfma_f32_32x32x16_bf16((a), (b), (c), 0, 0, 0)
#define MFMA16(a, b, c) __builtin_amdgcn_mfma_f32_16x16x32_bf16((a), (b), (c), 0, 0, 0)
#define LGKM0() asm volatile("s_waitcnt lgkmcnt(0)" ::: "memory")

static constexpr int kS = 2048, kD = 1024, kH = 16, kDH = 64, kM = 4096;

__device__ __forceinline__ void gload16(const void* g, void* lds) {
  __builtin_amdgcn_global_load_lds((const __attribute__((address_space(1))) void*)g,
                                   (__attribute__((address_space(3))) void*)lds, 16, 0, 0);
}

__device__ __forceinline__ float fexp2(float x) {
#if __has_builtin(__builtin_amdgcn_exp2f)
  return __builtin_amdgcn_exp2f(x);
#else
  return exp2f(x);
#endif
}

// ---- transpose + convert weights: Wt[n][k] = W[k][n] ----------------------
__global__ void __launch_bounds__(256) cvt_w_kernel(
    const float* __restrict__ w0, const float* __restrict__ w1,
    const float* __restrict__ w2, const float* __restrict__ w3,
    bf16* __restrict__ o0, bf16* __restrict__ o1, bf16* __restrict__ o2, bf16* __restrict__ o3) {
  const float* w = blockIdx.z == 0 ? w0 : blockIdx.z == 1 ? w1 : blockIdx.z == 2 ? w2 : w3;
  bf16* o       = blockIdx.z == 0 ? o0 : blockIdx.z == 1 ? o1 : blockIdx.z == 2 ? o2 : o3;
  __shared__ float t[32][33];
  int tx = threadIdx.x, ty = threadIdx.y;
  int k0 = blockIdx.x * 32, n0 = blockIdx.y * 32;
#pragma unroll
  for (int j = 0; j < 4; ++j)
    t[ty + j * 8][tx] = w[(size_t)(k0 + ty + j * 8) * kD + n0 + tx];
  __syncthreads();
#pragma unroll
  for (int j = 0; j < 4; ++j)
    o[(size_t)(n0 + ty + j * 8) * kD + k0 + tx] = (bf16)t[tx][ty + j * 8];
}

// ---- GEMM: C[128 x BN] tiles, A [M][1024] (fp32 fused-cvt or bf16), -------
// Wt [N][K] bf16. 2-barrier K-loop, global_load_lds w=16, XOR-swizzled LDS.
struct GemmArgs {
  const void* A;
  const bf16* Wt;
  const float* bias;
  void* out;
  float scale;
  int omode;  // 0: f32 [M][N]; 1: bf16 [b][h][s][dh]; 2: bf16 [b][h][dh][s]
};

template <int BN, bool AFP32>
__global__ void __launch_bounds__(256) gemm_kernel(GemmArgs ga, GemmArgs gb, GemmArgs gc) {
  GemmArgs g = blockIdx.z == 0 ? ga : blockIdx.z == 1 ? gb : gc;
  constexpr int WN = BN / 2, NJ = WN / 16;
  __shared__ __align__(16) char smem_raw[18432];
  bf16* As = (bf16*)smem_raw;                 // [128][32] swizzled slots
  bf16* Bs = (bf16*)(smem_raw + 8192);        // [BN][32] swizzled slots
  const int tid = threadIdx.x, wid = tid >> 6, lane = tid & 63;
  const int g4 = lane >> 4, l16 = lane & 15;
  const int m0 = blockIdx.x * 128, n0 = blockIdx.y * BN;
  const int wr = wid >> 1, wc = wid & 1;
  const bf16* Wt = g.Wt;

  // A fp32 reg-staging: thread -> row ar, k-half ah (16 floats / K-step)
  const int ar = tid >> 1, ah = tid & 1;
  const float* gAf = (const float*)g.A + (size_t)(m0 + ar) * kD + ah * 16;
  bf16* adst0 = As + ar * 32 + ((2 * ah) ^ ((ar >> 1) & 3)) * 8;
  bf16* adst1 = As + ar * 32 + ((2 * ah + 1) ^ ((ar >> 1) & 3)) * 8;

  const int xorv = (l16 >> 1) & 3;
  f32x4v acc[4][NJ] = {};

  for (int k0 = 0; k0 < kD; k0 += 32) {
    __syncthreads();
    if constexpr (AFP32) {
      float4 f0 = *(const float4*)(gAf + k0);
      float4 f1 = *(const float4*)(gAf + k0 + 4);
      float4 f2 = *(const float4*)(gAf + k0 + 8);
      float4 f3 = *(const float4*)(gAf + k0 + 12);
#pragma unroll
      for (int i = 0; i < BN / 64; ++i) {
        int id = i * 256 + tid;
        int row = id >> 2, c = id & 3;
        gload16(Wt + (size_t)(n0 + row) * kD + k0 + ((c ^ ((row >> 1) & 3)) * 8),
                Bs + (i * 256 + wid * 64) * 8);
      }
      bf16x8v c0 = {(bf16)f0.x, (bf16)f0.y, (bf16)f0.z, (bf16)f0.w,
                    (bf16)f1.x, (bf16)f1.y, (bf16)f1.z, (bf16)f1.w};
      bf16x8v c1 = {(bf16)f2.x, (bf16)f2.y, (bf16)f2.z, (bf16)f2.w,
                    (bf16)f3.x, (bf16)f3.y, (bf16)f3.z, (bf16)f3.w};
      *(bf16x8v*)adst0 = c0;
      *(bf16x8v*)adst1 = c1;
    } else {
      const bf16* Ab = (const bf16*)g.A;
#pragma unroll
      for (int i = 0; i < 2; ++i) {
        int id = i * 256 + tid;
        int row = id >> 2, c = id & 3;
        gload16(Ab + (size_t)(m0 + row) * kD + k0 + ((c ^ ((row >> 1) & 3)) * 8),
                As + (i * 256 + wid * 64) * 8);
      }
#pragma unroll
      for (int i = 0; i < BN / 64; ++i) {
        int id = i * 256 + tid;
        int row = id >> 2, c = id & 3;
        gload16(Wt + (size_t)(n0 + row) * kD + k0 + ((c ^ ((row >> 1) & 3)) * 8),
                Bs + (i * 256 + wid * 64) * 8);
      }
    }
    __syncthreads();
    bf16x8v af[4], bfr[NJ];
#pragma unroll
    for (int i = 0; i < 4; ++i) {
      int rowA = wr * 64 + i * 16 + l16;
      af[i] = *(const bf16x8v*)(As + rowA * 32 + ((g4 ^ xorv) * 8));
    }
#pragma unroll
    for (int j = 0; j < NJ; ++j) {
      int rowB = wc * WN + j * 16 + l16;
      bfr[j] = *(const bf16x8v*)(Bs + rowB * 32 + ((g4 ^ xorv) * 8));
    }
#pragma unroll
    for (int i = 0; i < 4; ++i)
#pragma unroll
      for (int j = 0; j < NJ; ++j)
        acc[i][j] = MFMA16(af[i], bfr[j], acc[i][j]);
  }

  // ---- epilogue via per-wave LDS bounce (vectorized stores) ----
  __syncthreads();  // staging region now reusable
  float* bws = (float*)smem_raw + wid * 1152;  // 4608 B per wave
  const int bb = m0 >> 11;

  if (g.omode == 1) {  // bf16 [b][h][s][dh]
    const int h = (n0 >> 6) + wc;
    float bj[NJ];
#pragma unroll
    for (int j = 0; j < NJ; ++j) bj[j] = g.bias[n0 + wc * WN + j * 16 + l16];
#pragma unroll
    for (int i = 0; i < 4; ++i) {
#pragma unroll
      for (int j = 0; j < NJ; ++j)
#pragma unroll
        for (int r = 0; r < 4; ++r)
          bws[(g4 * 4 + r) * 68 + j * 16 + l16] = (acc[i][j][r] + bj[j]) * g.scale;
      LGKM0();
      int rr = lane & 15, q = lane >> 4;
      const float* src = bws + rr * 68 + q * 16;
      f32x4v v0 = *(const f32x4v*)(src);
      f32x4v v1 = *(const f32x4v*)(src + 4);
      f32x4v v2 = *(const f32x4v*)(src + 8);
      f32x4v v3 = *(const f32x4v*)(src + 12);
      bf16x8v o0 = {(bf16)v0.x, (bf16)v0.y, (bf16)v0.z, (bf16)v0.w,
                    (bf16)v1.x, (bf16)v1.y, (bf16)v1.z, (bf16)v1.w};
      bf16x8v o1 = {(bf16)v2.x, (bf16)v2.y, (bf16)v2.z, (bf16)v2.w,
                    (bf16)v3.x, (bf16)v3.y, (bf16)v3.z, (bf16)v3.w};
      int srow = m0 + wr * 64 + i * 16 + rr;
      bf16* dst = (bf16*)g.out + ((size_t)(bb * kH + h) * kS + (srow & (kS - 1))) * kDH + q * 16;
      *(bf16x8v*)dst = o0;
      *(bf16x8v*)(dst + 8) = o1;
      LGKM0();
    }
  } else if (g.omode == 2) {  // bf16 [b][h][dh][s]  (transposed bounce)
    const int h = (n0 >> 6) + wc;
#pragma unroll
    for (int j = 0; j < NJ; ++j) {
      float bj = g.bias[n0 + wc * WN + j * 16 + l16];
#pragma unroll
      for (int i = 0; i < 4; ++i)
#pragma unroll
        for (int r = 0; r < 4; ++r)
          bws[l16 * 72 + i * 16 + g4 * 4 + r] = acc[i][j][r] + bj;
      LGKM0();
#pragma unroll
      for (int cc = 0; cc < 4; ++cc) {
        int id = cc * 64 + lane;
        int row = id >> 4, c = id & 15;
        f32x4v v = *(const f32x4v*)(bws + row * 72 + c * 4);
        bf16x4v ov = {(bf16)v.x, (bf16)v.y, (bf16)v.z, (bf16)v.w};
        int dh = j * 16 + row;
        int sg = m0 + wr * 64 + c * 4;
        *(bf16x4v*)((bf16*)g.out +
                    ((size_t)(bb * kH + h) * kDH + dh) * kS + (sg & (kS - 1))) = ov;
      }
      LGKM0();
    }
  } else {  // fp32 [M][N]
    float bj[NJ];
#pragma unroll
    for (int j = 0; j < NJ; ++j) bj[j] = g.bias[n0 + wc * WN + j * 16 + l16];
#pragma unroll
    for (int i = 0; i < 4; ++i) {
#pragma unroll
      for (int j = 0; j < NJ; ++j)
#pragma unroll
        for (int r = 0; r < 4; ++r)
          bws[(g4 * 4 + r) * 36 + j * 16 + l16] = acc[i][j][r] + bj[j];
      LGKM0();
#pragma unroll
      for (int cc = 0; cc < 2; ++cc) {
        int row = lane >> 2, ch = cc * 4 + (lane & 3);
        f32x4v v = *(const f32x4v*)(bws + row * 36 + ch * 4);
        int srow = m0 + wr * 64 + i * 16 + row;
        *(f32x4v*)((float*)g.out + (size_t)srow * kD + n0 + wc * WN + ch * 4) = v;
      }
      LGKM0();
    }
  }
}

// ---- causal flash attention (v4: KVBLK=128) -------------------------------
// Block = 128 q-rows = 4 waves x 32. K [128][64] + V^T [64][128] in LDS,
// double-buffered (64 KB), XOR-swizzled via pre-swizzled global source.
// Swapped MFMA32 (S^T = K x Q, O^T = V^T x P^T), in-register softmax via
// permlane32_swap + cvt_pk (T12). Per-sub causal skipping in diagonal tiles.
__global__ void __launch_bounds__(256) attn_kernel(
    const bf16* __restrict__ Qp, const bf16* __restrict__ Kp,
    const bf16* __restrict__ Vt, bf16* __restrict__ ctx) {
  __shared__ __align__(16) bf16 lds[32768];  // 64 KB: buf x {K 16KB, V 16KB}
  const int tid = threadIdx.x;
  const int wid = tid >> 6, lane = tid & 63;
  const int l32 = lane & 31, hi = lane >> 5;
  const int bh = blockIdx.x;
  const int qt = blockIdx.y;
  const int q0 = qt * 128;
  const int qw = q0 + wid * 32;
  const bf16* Qh = Qp + (size_t)bh * kS * kDH;
  const bf16* Kh = Kp + (size_t)bh * kS * kDH;
  const bf16* Vh = Vt + (size_t)bh * kDH * kS;

  bf16x8v qf[4];
#pragma unroll
  for (int kw = 0; kw < 4; ++kw)
    qf[kw] = *(const bf16x8v*)(Qh + (size_t)(qw + l32) * kDH + kw * 16 + hi * 8);

  f32x16v oacc[2] = {};
  float mreg = -1e30f, lsum = 0.f;
  const int q_lane = qw + l32;

  const int nt = qt + 1;  // kv tiles of 128

  auto stage = [&](int buf, int k0) {
    bf16* kd = &lds[buf * 16384];
    bf16* vd = kd + 8192;
#pragma unroll
    for (int i = 0; i < 4; ++i) {
      int id = i * 256 + tid;
      int kr = id >> 3, kc = id & 7;
      gload16(Kh + (size_t)(k0 + kr) * kDH + ((kc ^ (kr & 7)) * 8),
              kd + (i * 256 + wid * 64) * 8);
      int vr = id >> 4, vc = id & 15;
      gload16(Vh + (size_t)vr * kS + k0 + ((vc ^ (vr & 15)) * 8),
              vd + (i * 256 + wid * 64) * 8);
    }
  };

  stage(0, 0);
  __syncthreads();
  int cur = 0;
  for (int t = 0; t < nt; ++t) {
    const int k0 = t * 128;
    if (t + 1 < nt) stage(cur ^ 1, k0 + 128);
    const bf16* kb = &lds[cur * 16384];
    const bf16* vb = kb + 8192;

    bool live[4];
#pragma unroll
    for (int sub = 0; sub < 4; ++sub) live[sub] = (k0 + sub * 32 <= qw + 31);

    f32x16v st[4];
#pragma unroll
    for (int sub = 0; sub < 4; ++sub) {
      if (live[sub]) {
        int row = sub * 32 + l32;
        const bf16* krow = kb + row * 64;
        int rx = row & 7;
        f32x16v s = {};
#pragma unroll
        for (int kw = 0; kw < 4; ++kw) {
          bf16x8v af = *(const bf16x8v*)(krow + (((kw * 2 + hi) ^ rx) * 8));
          s = MFMA32(af, qf[kw], s);
        }
        st[sub] = s;
      }
    }
    if (k0 + 127 > qw) {  // diagonal: causal mask
#pragma unroll
      for (int sub = 0; sub < 4; ++sub)
        if (live[sub])
#pragma unroll
          for (int r = 0; r < 16; ++r) {
            int kv = k0 + sub * 32 + (r & 3) + 8 * (r >> 2) + 4 * hi;
            if (kv > q_lane) st[sub][r] = -1e30f;
          }
    }
    // softmax (log2 domain): in-lane reduce + one cross-half swap
    float rm = -1e30f;
#pragma unroll
    for (int sub = 0; sub < 4; ++sub)
      if (live[sub])
#pragma unroll
        for (int r = 0; r < 16; ++r) rm = fmaxf(rm, st[sub][r]);
    {
      uint32x2v sw = __builtin_amdgcn_permlane32_swap(
          __float_as_uint(rm), __float_as_uint(rm), false, false);
      rm = fmaxf(rm, __uint_as_float(hi ? sw.x : sw.y));
    }
    float mn = fmaxf(mreg, rm);
    float al = fexp2(mreg - mn);
    mreg = mn;
    float rs = 0.f;
    unsigned int w[32];
#pragma unroll
    for (int sub = 0; sub < 4; ++sub) {
      if (live[sub]) {
#pragma unroll
        for (int i = 0; i < 8; ++i) {
          float p0 = fexp2(st[sub][2 * i] - mn);
          float p1 = fexp2(st[sub][2 * i + 1] - mn);
          rs += p0 + p1;
          union { bf16x2v h; unsigned int u; } cv;
          cv.h = bf16x2v{(bf16)p0, (bf16)p1};
          w[sub * 8 + i] = cv.u;
        }
      }
    }
    {
      uint32x2v sw = __builtin_amdgcn_permlane32_swap(
          __float_as_uint(rs), __float_as_uint(rs), false, false);
      rs += __uint_as_float(hi ? sw.x : sw.y);
    }
    lsum = lsum * al + rs;
#pragma unroll
    for (int s = 0; s < 2; ++s)
#pragma unroll
      for (int r = 0; r < 16; ++r) oacc[s][r] *= al;

    // PV over live 16-kv windows
#pragma unroll
    for (int f = 0; f < 8; ++f) {
      if (k0 + f * 16 <= qw + 31) {
        uint32x2v r0 = __builtin_amdgcn_permlane32_swap(w[4 * f], w[4 * f + 2], false, false);
        uint32x2v r1 = __builtin_amdgcn_permlane32_swap(w[4 * f + 1], w[4 * f + 3], false, false);
        union { unsigned int u[4]; bf16x8v h; } fu;
        fu.u[0] = r0.x; fu.u[1] = r1.x; fu.u[2] = r0.y; fu.u[3] = r1.y;
        int cw = f * 2 + hi;
#pragma unroll
        for (int s = 0; s < 2; ++s) {
          int row = s * 32 + l32;
          bf16x8v vf = *(const bf16x8v*)(vb + row * 128 + ((cw ^ (row & 15)) * 8));
          oacc[s] = MFMA32(vf, fu.h, oacc[s]);
        }
      }
    }
    __syncthreads();
    cur ^= 1;
  }

  float inv = 1.0f / lsum;
  const int b = bh >> 4, h = bh & 15;
  bf16* crow = ctx + (size_t)(b * kS + qw + l32) * kD + h * 64;
#pragma unroll
  for (int s = 0; s < 2; ++s)
#pragma unroll
    for (int rq = 0; rq < 4; ++rq) {
      union { bf16x4v h; uint32x2v u; } pk;
      pk.h = bf16x4v{(bf16)(oacc[s][rq * 4 + 0] * inv), (bf16)(oacc[s][rq * 4 + 1] * inv),
                     (bf16)(oacc[s][rq * 4 + 2] * inv), (bf16)(oacc[s][rq * 4 + 3] * inv)};
      *(uint32x2v*)(crow + 8 * rq + 4 * hi + 32 * s) = pk.u;
    }
}

// ---------------------------------------------------------------------------
extern "C" void kernel_launch(void* const* d_in, const int* in_sizes, int n_in,
                              void* d_out, int out_size, void* d_ws, size_t ws_size,
                              hipStream_t stream) {
  (void)in_sizes; (void)n_in; (void)out_size; (void)ws_size;
  const float* q  = (const float*)d_in[0];
  const float* k  = (const float*)d_in[1];
  const float* v  = (const float*)d_in[2];
  // d_in[3] = causal mask, structure hardcoded
  const float* Wq = (const float*)d_in[4];
  const float* bq = (const float*)d_in[5];
  const float* Wk = (const float*)d_in[6];
  const float* bk = (const float*)d_in[7];
  const float* Wv = (const float*)d_in[8];
  const float* bv = (const float*)d_in[9];
  const float* Wo = (const float*)d_in[10];
  const float* bo = (const float*)d_in[11];

  char* p = (char*)d_ws;
  auto carve = [&](size_t bytes) {
    char* r = p;
    p += (bytes + 255) & ~(size_t)255;
    return r;
  };
  const size_t XB = (size_t)kM * kD * sizeof(bf16);  // 8 MB
  const size_t WB = (size_t)kD * kD * sizeof(bf16);  // 2 MB
  bf16* Wtq = (bf16*)carve(WB);
  bf16* Wtk = (bf16*)carve(WB);
  bf16* Wtv = (bf16*)carve(WB);
  bf16* Wto = (bf16*)carve(WB);
  bf16* Qp  = (bf16*)carve(XB);  // [b][h][s][dh], pre-scaled (log2 domain)
  bf16* Kp  = (bf16*)carve(XB);  // [b][h][s][dh]
  bf16* Vt  = (bf16*)carve(XB);  // [b][h][dh][s]
  bf16* Ctx = (bf16*)carve(XB);  // [b*s][d]

  cvt_w_kernel<<<dim3(32, 32, 4), dim3(32, 8, 1), 0, stream>>>(Wq, Wk, Wv, Wo,
                                                               Wtq, Wtk, Wtv, Wto);
  // fold 1/sqrt(DH) * log2(e) into Q (softmax runs in log2 domain)
  GemmArgs aq{q, Wtq, bq, Qp, 0.125f * 1.44269504f, 1};
  GemmArgs ak{k, Wtk, bk, Kp, 1.0f, 1};
  GemmArgs av{v, Wtv, bv, Vt, 1.0f, 2};
  gemm_kernel<128, true><<<dim3(32, 8, 3), 256, 0, stream>>>(aq, ak, av);
  attn_kernel<<<dim3(32, 16), 256, 0, stream>>>(Qp, Kp, Vt, Ctx);
  GemmArgs ao{Ctx, Wto, bo, d_out, 1.0f, 0};
  gemm_kernel<64, false><<<dim3(32, 16, 1), 256, 0, stream>>>(ao, ao, ao);
}

// Round 8
// 305.525 us; speedup vs baseline: 1.0136x; 1.0136x over previous
//
#include <hip/hip_runtime.h>
#include <hip/hip_bf16.h>
#include <stdint.h>

// ---------------------------------------------------------------------------
// Fused MHA: QKV GEMMs (fp32-A fused cvt, bf16 MFMA, double-buffered LDS
// pipeline, vectorized head-major epilogues) -> causal flash attention
// (KVBLK=128, swapped 32x32 MFMA, in-register softmax) -> output GEMM.
// ---------------------------------------------------------------------------

typedef __bf16 bf16;
typedef __bf16 bf16x2v __attribute__((ext_vector_type(2)));
typedef __bf16 bf16x4v __attribute__((ext_vector_type(4)));
typedef __bf16 bf16x8v __attribute__((ext_vector_type(8)));
typedef float  f32x4v  __attribute__((ext_vector_type(4)));
typedef float  f32x16v __attribute__((ext_vector_type(16)));
typedef unsigned int uint32x2v __attribute__((ext_vector_type(2)));

#define MFMA32(a, b, c) __builtin_amdgcn_mfma_f32_32x32x16_bf16((a), (b), (c), 0, 0, 0)
#define MFMA16(a, b, c) __builtin_amdgcn_mfma_f32_16x16x32_bf16((a), (b), (c), 0, 0, 0)
#define LGKM0() asm volatile("s_waitcnt lgkmcnt(0)" ::: "memory")

static constexpr int kS = 2048, kD = 1024, kH = 16, kDH = 64, kM = 4096;

__device__ __forceinline__ void gload16(const void* g, void* lds) {
  __builtin_amdgcn_global_load_lds((const __attribute__((address_space(1))) void*)g,
                                   (__attribute__((address_space(3))) void*)lds, 16, 0, 0);
}

__device__ __forceinline__ float fexp2(float x) {
#if __has_builtin(__builtin_amdgcn_exp2f)
  return __builtin_amdgcn_exp2f(x);
#else
  return exp2f(x);
#endif
}

// ---- transpose + convert weights: Wt[n][k] = W[k][n] ----------------------
__global__ void __launch_bounds__(256) cvt_w_kernel(
    const float* __restrict__ w0, const float* __restrict__ w1,
    const float* __restrict__ w2, const float* __restrict__ w3,
    bf16* __restrict__ o0, bf16* __restrict__ o1, bf16* __restrict__ o2, bf16* __restrict__ o3) {
  const float* w = blockIdx.z == 0 ? w0 : blockIdx.z == 1 ? w1 : blockIdx.z == 2 ? w2 : w3;
  bf16* o       = blockIdx.z == 0 ? o0 : blockIdx.z == 1 ? o1 : blockIdx.z == 2 ? o2 : o3;
  __shared__ float t[32][33];
  int tx = threadIdx.x, ty = threadIdx.y;
  int k0 = blockIdx.x * 32, n0 = blockIdx.y * 32;
#pragma unroll
  for (int j = 0; j < 4; ++j)
    t[ty + j * 8][tx] = w[(size_t)(k0 + ty + j * 8) * kD + n0 + tx];
  __syncthreads();
#pragma unroll
  for (int j = 0; j < 4; ++j)
    o[(size_t)(n0 + ty + j * 8) * kD + k0 + tx] = (bf16)t[tx][ty + j * 8];
}

// ---- GEMM: C[128 x BN] tiles, A [M][1024] (fp32 fused-cvt or bf16), -------
// Wt [N][K] bf16. Double-buffered LDS pipeline (T14): issue next tile's
// loads before computing current; single barrier per K-step.
struct GemmArgs {
  const void* A;
  const bf16* Wt;
  const float* bias;
  void* out;
  float scale;
  int omode;  // 0: f32 [M][N]; 1: bf16 [b][h][s][dh]; 2: bf16 [b][h][dh][s]
};

template <int BN, bool AFP32>
__global__ void __launch_bounds__(256) gemm_kernel(GemmArgs ga, GemmArgs gb, GemmArgs gc) {
  GemmArgs g = blockIdx.z == 0 ? ga : blockIdx.z == 1 ? gb : gc;
  constexpr int WN = BN / 2, NJ = WN / 16;
  constexpr int ASZ = 128 * 32;   // elems per A buffer (8 KB)
  constexpr int BSZ = BN * 32;    // elems per B buffer
  __shared__ __align__(16) bf16 smem[2 * ASZ + 2 * BSZ];
  const int tid = threadIdx.x, wid = tid >> 6, lane = tid & 63;
  const int g4 = lane >> 4, l16 = lane & 15;
  const int m0 = blockIdx.x * 128, n0 = blockIdx.y * BN;
  const int wr = wid >> 1, wc = wid & 1;
  const bf16* Wt = g.Wt;

  // A fp32 reg-staging: thread -> row ar, k-half ah (16 floats / K-step)
  const int ar = tid >> 1, ah = tid & 1;
  const float* gAf = (const float*)g.A + (size_t)(m0 + ar) * kD + ah * 16;
  const int aoff0 = ar * 32 + ((2 * ah) ^ ((ar >> 1) & 3)) * 8;
  const int aoff1 = ar * 32 + ((2 * ah + 1) ^ ((ar >> 1) & 3)) * 8;

  float4 f0, f1, f2, f3;  // A prefetch registers (fp32 path)
  auto loadA = [&](int k0) {
    f0 = *(const float4*)(gAf + k0);
    f1 = *(const float4*)(gAf + k0 + 4);
    f2 = *(const float4*)(gAf + k0 + 8);
    f3 = *(const float4*)(gAf + k0 + 12);
  };
  auto writeA = [&](bf16* As) {
    bf16x8v c0 = {(bf16)f0.x, (bf16)f0.y, (bf16)f0.z, (bf16)f0.w,
                  (bf16)f1.x, (bf16)f1.y, (bf16)f1.z, (bf16)f1.w};
    bf16x8v c1 = {(bf16)f2.x, (bf16)f2.y, (bf16)f2.z, (bf16)f2.w,
                  (bf16)f3.x, (bf16)f3.y, (bf16)f3.z, (bf16)f3.w};
    *(bf16x8v*)(As + aoff0) = c0;
    *(bf16x8v*)(As + aoff1) = c1;
  };
  auto stageA_lds = [&](int k0, bf16* As) {  // bf16 path
    const bf16* Ab = (const bf16*)g.A;
#pragma unroll
    for (int i = 0; i < 2; ++i) {
      int id = i * 256 + tid;
      int row = id >> 2, c = id & 3;
      gload16(Ab + (size_t)(m0 + row) * kD + k0 + ((c ^ ((row >> 1) & 3)) * 8),
              As + (i * 256 + wid * 64) * 8);
    }
  };
  auto stageB = [&](int k0, bf16* Bs) {
#pragma unroll
    for (int i = 0; i < BN / 64; ++i) {
      int id = i * 256 + tid;
      int row = id >> 2, c = id & 3;
      gload16(Wt + (size_t)(n0 + row) * kD + k0 + ((c ^ ((row >> 1) & 3)) * 8),
              Bs + (i * 256 + wid * 64) * 8);
    }
  };

  const int xorv = (l16 >> 1) & 3;
  f32x4v acc[4][NJ] = {};

  // prologue: fill buffer 0
  if constexpr (AFP32) {
    loadA(0);
    stageB(0, smem + 2 * ASZ);
    writeA(smem);
  } else {
    stageA_lds(0, smem);
    stageB(0, smem + 2 * ASZ);
  }
  __syncthreads();  // drains vmcnt+lgkm: buffer 0 ready

  constexpr int NT = kD / 32;
  for (int t = 0; t < NT; ++t) {
    const int c = t & 1;
    bf16* Asc = smem + c * ASZ;
    bf16* Bsc = smem + 2 * ASZ + c * BSZ;
    bf16* Asn = smem + (c ^ 1) * ASZ;
    bf16* Bsn = smem + 2 * ASZ + (c ^ 1) * BSZ;
    // issue next tile's loads early (hide latency under MFMA)
    if (t + 1 < NT) {
      if constexpr (AFP32) {
        loadA((t + 1) * 32);
      } else {
        stageA_lds((t + 1) * 32, Asn);
      }
      stageB((t + 1) * 32, Bsn);
    }
    bf16x8v af[4], bfr[NJ];
#pragma unroll
    for (int i = 0; i < 4; ++i) {
      int rowA = wr * 64 + i * 16 + l16;
      af[i] = *(const bf16x8v*)(Asc + rowA * 32 + ((g4 ^ xorv) * 8));
    }
#pragma unroll
    for (int j = 0; j < NJ; ++j) {
      int rowB = wc * WN + j * 16 + l16;
      bfr[j] = *(const bf16x8v*)(Bsc + rowB * 32 + ((g4 ^ xorv) * 8));
    }
#pragma unroll
    for (int i = 0; i < 4; ++i)
#pragma unroll
      for (int j = 0; j < NJ; ++j)
        acc[i][j] = MFMA16(af[i], bfr[j], acc[i][j]);
    if constexpr (AFP32) {
      if (t + 1 < NT) writeA(Asn);  // regs arrived during MFMA block
    }
    __syncthreads();  // next buffer ready; current reads complete
  }

  // ---- epilogue via per-wave LDS bounce (vectorized stores) ----
  float* bws = (float*)smem + wid * 1152;  // 4608 B per wave
  const int bb = m0 >> 11;

  if (g.omode == 1) {  // bf16 [b][h][s][dh]
    const int h = (n0 >> 6) + wc;
    float bj[NJ];
#pragma unroll
    for (int j = 0; j < NJ; ++j) bj[j] = g.bias[n0 + wc * WN + j * 16 + l16];
#pragma unroll
    for (int i = 0; i < 4; ++i) {
#pragma unroll
      for (int j = 0; j < NJ; ++j)
#pragma unroll
        for (int r = 0; r < 4; ++r)
          bws[(g4 * 4 + r) * 68 + j * 16 + l16] = (acc[i][j][r] + bj[j]) * g.scale;
      LGKM0();
      int rr = lane & 15, q = lane >> 4;
      const float* src = bws + rr * 68 + q * 16;
      f32x4v v0 = *(const f32x4v*)(src);
      f32x4v v1 = *(const f32x4v*)(src + 4);
      f32x4v v2 = *(const f32x4v*)(src + 8);
      f32x4v v3 = *(const f32x4v*)(src + 12);
      bf16x8v o0 = {(bf16)v0.x, (bf16)v0.y, (bf16)v0.z, (bf16)v0.w,
                    (bf16)v1.x, (bf16)v1.y, (bf16)v1.z, (bf16)v1.w};
      bf16x8v o1 = {(bf16)v2.x, (bf16)v2.y, (bf16)v2.z, (bf16)v2.w,
                    (bf16)v3.x, (bf16)v3.y, (bf16)v3.z, (bf16)v3.w};
      int srow = m0 + wr * 64 + i * 16 + rr;
      bf16* dst = (bf16*)g.out + ((size_t)(bb * kH + h) * kS + (srow & (kS - 1))) * kDH + q * 16;
      *(bf16x8v*)dst = o0;
      *(bf16x8v*)(dst + 8) = o1;
      LGKM0();
    }
  } else if (g.omode == 2) {  // bf16 [b][h][dh][s]  (transposed bounce)
    const int h = (n0 >> 6) + wc;
#pragma unroll
    for (int j = 0; j < NJ; ++j) {
      float bj = g.bias[n0 + wc * WN + j * 16 + l16];
#pragma unroll
      for (int i = 0; i < 4; ++i)
#pragma unroll
        for (int r = 0; r < 4; ++r)
          bws[l16 * 72 + i * 16 + g4 * 4 + r] = acc[i][j][r] + bj;
      LGKM0();
#pragma unroll
      for (int cc = 0; cc < 4; ++cc) {
        int id = cc * 64 + lane;
        int row = id >> 4, c = id & 15;
        f32x4v v = *(const f32x4v*)(bws + row * 72 + c * 4);
        bf16x4v ov = {(bf16)v.x, (bf16)v.y, (bf16)v.z, (bf16)v.w};
        int dh = j * 16 + row;
        int sg = m0 + wr * 64 + c * 4;
        *(bf16x4v*)((bf16*)g.out +
                    ((size_t)(bb * kH + h) * kDH + dh) * kS + (sg & (kS - 1))) = ov;
      }
      LGKM0();
    }
  } else {  // fp32 [M][N]
    float bj[NJ];
#pragma unroll
    for (int j = 0; j < NJ; ++j) bj[j] = g.bias[n0 + wc * WN + j * 16 + l16];
#pragma unroll
    for (int i = 0; i < 4; ++i) {
#pragma unroll
      for (int j = 0; j < NJ; ++j)
#pragma unroll
        for (int r = 0; r < 4; ++r)
          bws[(g4 * 4 + r) * 36 + j * 16 + l16] = acc[i][j][r] + bj[j];
      LGKM0();
#pragma unroll
      for (int cc = 0; cc < 2; ++cc) {
        int row = lane >> 2, ch = cc * 4 + (lane & 3);
        f32x4v v = *(const f32x4v*)(bws + row * 36 + ch * 4);
        int srow = m0 + wr * 64 + i * 16 + row;
        *(f32x4v*)((float*)g.out + (size_t)srow * kD + n0 + wc * WN + ch * 4) = v;
      }
      LGKM0();
    }
  }
}

// ---- causal flash attention (v4: KVBLK=128) -------------------------------
// Block = 128 q-rows = 4 waves x 32. K [128][64] + V^T [64][128] in LDS,
// double-buffered (64 KB), XOR-swizzled via pre-swizzled global source.
// Swapped MFMA32 (S^T = K x Q, O^T = V^T x P^T), in-register softmax via
// permlane32_swap + cvt_pk (T12). Per-sub causal skipping in diagonal tiles.
__global__ void __launch_bounds__(256) attn_kernel(
    const bf16* __restrict__ Qp, const bf16* __restrict__ Kp,
    const bf16* __restrict__ Vt, bf16* __restrict__ ctx) {
  __shared__ __align__(16) bf16 lds[32768];  // 64 KB: buf x {K 16KB, V 16KB}
  const int tid = threadIdx.x;
  const int wid = tid >> 6, lane = tid & 63;
  const int l32 = lane & 31, hi = lane >> 5;
  const int bh = blockIdx.x;
  const int qt = blockIdx.y;
  const int q0 = qt * 128;
  const int qw = q0 + wid * 32;
  const bf16* Qh = Qp + (size_t)bh * kS * kDH;
  const bf16* Kh = Kp + (size_t)bh * kS * kDH;
  const bf16* Vh = Vt + (size_t)bh * kDH * kS;

  bf16x8v qf[4];
#pragma unroll
  for (int kw = 0; kw < 4; ++kw)
    qf[kw] = *(const bf16x8v*)(Qh + (size_t)(qw + l32) * kDH + kw * 16 + hi * 8);

  f32x16v oacc[2] = {};
  float mreg = -1e30f, lsum = 0.f;
  const int q_lane = qw + l32;

  const int nt = qt + 1;  // kv tiles of 128

  auto stage = [&](int buf, int k0) {
    bf16* kd = &lds[buf * 16384];
    bf16* vd = kd + 8192;
#pragma unroll
    for (int i = 0; i < 4; ++i) {
      int id = i * 256 + tid;
      int kr = id >> 3, kc = id & 7;
      gload16(Kh + (size_t)(k0 + kr) * kDH + ((kc ^ (kr & 7)) * 8),
              kd + (i * 256 + wid * 64) * 8);
      int vr = id >> 4, vc = id & 15;
      gload16(Vh + (size_t)vr * kS + k0 + ((vc ^ (vr & 15)) * 8),
              vd + (i * 256 + wid * 64) * 8);
    }
  };

  stage(0, 0);
  __syncthreads();
  int cur = 0;
  for (int t = 0; t < nt; ++t) {
    const int k0 = t * 128;
    if (t + 1 < nt) stage(cur ^ 1, k0 + 128);
    const bf16* kb = &lds[cur * 16384];
    const bf16* vb = kb + 8192;

    bool live[4];
#pragma unroll
    for (int sub = 0; sub < 4; ++sub) live[sub] = (k0 + sub * 32 <= qw + 31);

    f32x16v st[4];
#pragma unroll
    for (int sub = 0; sub < 4; ++sub) {
      if (live[sub]) {
        int row = sub * 32 + l32;
        const bf16* krow = kb + row * 64;
        int rx = row & 7;
        f32x16v s = {};
#pragma unroll
        for (int kw = 0; kw < 4; ++kw) {
          bf16x8v af = *(const bf16x8v*)(krow + (((kw * 2 + hi) ^ rx) * 8));
          s = MFMA32(af, qf[kw], s);
        }
        st[sub] = s;
      }
    }
    if (k0 + 127 > qw) {  // diagonal: causal mask
#pragma unroll
      for (int sub = 0; sub < 4; ++sub)
        if (live[sub])
#pragma unroll
          for (int r = 0; r < 16; ++r) {
            int kv = k0 + sub * 32 + (r & 3) + 8 * (r >> 2) + 4 * hi;
            if (kv > q_lane) st[sub][r] = -1e30f;
          }
    }
    // softmax (log2 domain): in-lane reduce + one cross-half swap
    float rm = -1e30f;
#pragma unroll
    for (int sub = 0; sub < 4; ++sub)
      if (live[sub])
#pragma unroll
        for (int r = 0; r < 16; ++r) rm = fmaxf(rm, st[sub][r]);
    {
      uint32x2v sw = __builtin_amdgcn_permlane32_swap(
          __float_as_uint(rm), __float_as_uint(rm), false, false);
      rm = fmaxf(rm, __uint_as_float(hi ? sw.x : sw.y));
    }
    float mn = fmaxf(mreg, rm);
    float al = fexp2(mreg - mn);
    mreg = mn;
    float rs = 0.f;
    unsigned int w[32];
#pragma unroll
    for (int sub = 0; sub < 4; ++sub) {
      if (live[sub]) {
#pragma unroll
        for (int i = 0; i < 8; ++i) {
          float p0 = fexp2(st[sub][2 * i] - mn);
          float p1 = fexp2(st[sub][2 * i + 1] - mn);
          rs += p0 + p1;
          union { bf16x2v h; unsigned int u; } cv;
          cv.h = bf16x2v{(bf16)p0, (bf16)p1};
          w[sub * 8 + i] = cv.u;
        }
      }
    }
    {
      uint32x2v sw = __builtin_amdgcn_permlane32_swap(
          __float_as_uint(rs), __float_as_uint(rs), false, false);
      rs += __uint_as_float(hi ? sw.x : sw.y);
    }
    lsum = lsum * al + rs;
#pragma unroll
    for (int s = 0; s < 2; ++s)
#pragma unroll
      for (int r = 0; r < 16; ++r) oacc[s][r] *= al;

    // PV over live 16-kv windows
#pragma unroll
    for (int f = 0; f < 8; ++f) {
      if (k0 + f * 16 <= qw + 31) {
        uint32x2v r0 = __builtin_amdgcn_permlane32_swap(w[4 * f], w[4 * f + 2], false, false);
        uint32x2v r1 = __builtin_amdgcn_permlane32_swap(w[4 * f + 1], w[4 * f + 3], false, false);
        union { unsigned int u[4]; bf16x8v h; } fu;
        fu.u[0] = r0.x; fu.u[1] = r1.x; fu.u[2] = r0.y; fu.u[3] = r1.y;
        int cw = f * 2 + hi;
#pragma unroll
        for (int s = 0; s < 2; ++s) {
          int row = s * 32 + l32;
          bf16x8v vf = *(const bf16x8v*)(vb + row * 128 + ((cw ^ (row & 15)) * 8));
          oacc[s] = MFMA32(vf, fu.h, oacc[s]);
        }
      }
    }
    __syncthreads();
    cur ^= 1;
  }

  float inv = 1.0f / lsum;
  const int b = bh >> 4, h = bh & 15;
  bf16* crow = ctx + (size_t)(b * kS + qw + l32) * kD + h * 64;
#pragma unroll
  for (int s = 0; s < 2; ++s)
#pragma unroll
    for (int rq = 0; rq < 4; ++rq) {
      union { bf16x4v h; uint32x2v u; } pk;
      pk.h = bf16x4v{(bf16)(oacc[s][rq * 4 + 0] * inv), (bf16)(oacc[s][rq * 4 + 1] * inv),
                     (bf16)(oacc[s][rq * 4 + 2] * inv), (bf16)(oacc[s][rq * 4 + 3] * inv)};
      *(uint32x2v*)(crow + 8 * rq + 4 * hi + 32 * s) = pk.u;
    }
}

// ---------------------------------------------------------------------------
extern "C" void kernel_launch(void* const* d_in, const int* in_sizes, int n_in,
                              void* d_out, int out_size, void* d_ws, size_t ws_size,
                              hipStream_t stream) {
  (void)in_sizes; (void)n_in; (void)out_size; (void)ws_size;
  const float* q  = (const float*)d_in[0];
  const float* k  = (const float*)d_in[1];
  const float* v  = (const float*)d_in[2];
  // d_in[3] = causal mask, structure hardcoded
  const float* Wq = (const float*)d_in[4];
  const float* bq = (const float*)d_in[5];
  const float* Wk = (const float*)d_in[6];
  const float* bk = (const float*)d_in[7];
  const float* Wv = (const float*)d_in[8];
  const float* bv = (const float*)d_in[9];
  const float* Wo = (const float*)d_in[10];
  const float* bo = (const float*)d_in[11];

  char* p = (char*)d_ws;
  auto carve = [&](size_t bytes) {
    char* r = p;
    p += (bytes + 255) & ~(size_t)255;
    return r;
  };
  const size_t XB = (size_t)kM * kD * sizeof(bf16);  // 8 MB
  const size_t WB = (size_t)kD * kD * sizeof(bf16);  // 2 MB
  bf16* Wtq = (bf16*)carve(WB);
  bf16* Wtk = (bf16*)carve(WB);
  bf16* Wtv = (bf16*)carve(WB);
  bf16* Wto = (bf16*)carve(WB);
  bf16* Qp  = (bf16*)carve(XB);  // [b][h][s][dh], pre-scaled (log2 domain)
  bf16* Kp  = (bf16*)carve(XB);  // [b][h][s][dh]
  bf16* Vt  = (bf16*)carve(XB);  // [b][h][dh][s]
  bf16* Ctx = (bf16*)carve(XB);  // [b*s][d]

  cvt_w_kernel<<<dim3(32, 32, 4), dim3(32, 8, 1), 0, stream>>>(Wq, Wk, Wv, Wo,
                                                               Wtq, Wtk, Wtv, Wto);
  // fold 1/sqrt(DH) * log2(e) into Q (softmax runs in log2 domain)
  GemmArgs aq{q, Wtq, bq, Qp, 0.125f * 1.44269504f, 1};
  GemmArgs ak{k, Wtk, bk, Kp, 1.0f, 1};
  GemmArgs av{v, Wtv, bv, Vt, 1.0f, 2};
  gemm_kernel<128, true><<<dim3(32, 8, 3), 256, 0, stream>>>(aq, ak, av);
  attn_kernel<<<dim3(32, 16), 256, 0, stream>>>(Qp, Kp, Vt, Ctx);
  GemmArgs ao{Ctx, Wto, bo, d_out, 1.0f, 0};
  gemm_kernel<64, false><<<dim3(32, 16, 1), 256, 0, stream>>>(ao, ao, ao);
}

// Round 9
// 239.661 us; speedup vs baseline: 1.2921x; 1.2748x over previous
//
#include <hip/hip_runtime.h>
#include <hip/hip_bf16.h>
#include <stdint.h>

// ---------------------------------------------------------------------------
// Fused MHA: cvt(fp32->bf16) -> QKV GEMMs (bf16 MFMA, BN=64 tiles, dbuf
// gload_lds pipeline, vectorized head-major epilogues) -> causal flash
// attention (v3: KVBLK=64, swapped 32x32 MFMA, in-register softmax)
// -> output GEMM (BN=64, fp32 out).
// ---------------------------------------------------------------------------

typedef __bf16 bf16;
typedef __bf16 bf16x2v __attribute__((ext_vector_type(2)));
typedef __bf16 bf16x4v __attribute__((ext_vector_type(4)));
typedef __bf16 bf16x8v __attribute__((ext_vector_type(8)));
typedef float  f32x4v  __attribute__((ext_vector_type(4)));
typedef float  f32x16v __attribute__((ext_vector_type(16)));
typedef unsigned int uint32x2v __attribute__((ext_vector_type(2)));

#define MFMA32(a, b, c) __builtin_amdgcn_mfma_f32_32x32x16_bf16((a), (b), (c), 0, 0, 0)
#define MFMA16(a, b, c) __builtin_amdgcn_mfma_f32_16x16x32_bf16((a), (b), (c), 0, 0, 0)
#define LGKM0() asm volatile("s_waitcnt lgkmcnt(0)" ::: "memory")

static constexpr int kS = 2048, kD = 1024, kH = 16, kDH = 64, kM = 4096;

__device__ __forceinline__ void gload16(const void* g, void* lds) {
  __builtin_amdgcn_global_load_lds((const __attribute__((address_space(1))) void*)g,
                                   (__attribute__((address_space(3))) void*)lds, 16, 0, 0);
}

__device__ __forceinline__ float fexp2(float x) {
#if __has_builtin(__builtin_amdgcn_exp2f)
  return __builtin_amdgcn_exp2f(x);
#else
  return exp2f(x);
#endif
}

// ---- convert q,k,v fp32 -> bf16 (vectorized, G13) -------------------------
__global__ void __launch_bounds__(256) cvt_x_kernel(
    const float* __restrict__ q, const float* __restrict__ k, const float* __restrict__ v,
    bf16* __restrict__ xq, bf16* __restrict__ xk, bf16* __restrict__ xv) {
  int i = (blockIdx.x * 256 + threadIdx.x) * 4;
  float4 a = *(const float4*)(q + i);
  float4 b = *(const float4*)(k + i);
  float4 c = *(const float4*)(v + i);
  bf16x4v oa = {(bf16)a.x, (bf16)a.y, (bf16)a.z, (bf16)a.w};
  bf16x4v ob = {(bf16)b.x, (bf16)b.y, (bf16)b.z, (bf16)b.w};
  bf16x4v oc = {(bf16)c.x, (bf16)c.y, (bf16)c.z, (bf16)c.w};
  *(bf16x4v*)(xq + i) = oa;
  *(bf16x4v*)(xk + i) = ob;
  *(bf16x4v*)(xv + i) = oc;
}

// ---- transpose + convert weights: Wt[n][k] = W[k][n] ----------------------
__global__ void __launch_bounds__(256) cvt_w_kernel(
    const float* __restrict__ w0, const float* __restrict__ w1,
    const float* __restrict__ w2, const float* __restrict__ w3,
    bf16* __restrict__ o0, bf16* __restrict__ o1, bf16* __restrict__ o2, bf16* __restrict__ o3) {
  const float* w = blockIdx.z == 0 ? w0 : blockIdx.z == 1 ? w1 : blockIdx.z == 2 ? w2 : w3;
  bf16* o       = blockIdx.z == 0 ? o0 : blockIdx.z == 1 ? o1 : blockIdx.z == 2 ? o2 : o3;
  __shared__ float t[32][33];
  int tx = threadIdx.x, ty = threadIdx.y;
  int k0 = blockIdx.x * 32, n0 = blockIdx.y * 32;
#pragma unroll
  for (int j = 0; j < 4; ++j)
    t[ty + j * 8][tx] = w[(size_t)(k0 + ty + j * 8) * kD + n0 + tx];
  __syncthreads();
#pragma unroll
  for (int j = 0; j < 4; ++j)
    o[(size_t)(n0 + ty + j * 8) * kD + k0 + tx] = (bf16)t[tx][ty + j * 8];
}

// ---- GEMM: C[128 x 64] tiles, A [M][1024] bf16, Wt [N][K] bf16. -----------
// Double-buffered gload_lds pipeline; 24 KB LDS -> ~5 blocks/CU (latency
// hiding via occupancy). Vectorized LDS-bounce epilogues.
struct GemmArgs {
  const bf16* A;
  const bf16* Wt;
  const float* bias;
  void* out;
  float scale;
  int omode;  // 0: f32 [M][N]; 1: bf16 [b][h][s][dh]; 2: bf16 [b][h][dh][s]
};

__global__ void __launch_bounds__(256) gemm_kernel(GemmArgs ga, GemmArgs gb, GemmArgs gc) {
  GemmArgs g = blockIdx.z == 0 ? ga : blockIdx.z == 1 ? gb : gc;
  constexpr int BN = 64, WN = 32, NJ = 2;
  constexpr int ASZ = 128 * 32;  // 8 KB per A buffer
  constexpr int BSZ = BN * 32;   // 4 KB per B buffer
  __shared__ __align__(16) bf16 smem[2 * ASZ + 2 * BSZ];  // 24 KB
  const int tid = threadIdx.x, wid = tid >> 6, lane = tid & 63;
  const int g4 = lane >> 4, l16 = lane & 15;
  const int m0 = blockIdx.x * 128, n0 = blockIdx.y * BN;
  const int wr = wid >> 1, wc = wid & 1;
  const bf16* Wt = g.Wt;

  auto stageA = [&](int k0, bf16* As) {
#pragma unroll
    for (int i = 0; i < 2; ++i) {
      int id = i * 256 + tid;
      int row = id >> 2, c = id & 3;
      gload16(g.A + (size_t)(m0 + row) * kD + k0 + ((c ^ ((row >> 1) & 3)) * 8),
              As + (i * 256 + wid * 64) * 8);
    }
  };
  auto stageB = [&](int k0, bf16* Bs) {
    int row = tid >> 2, c = tid & 3;
    gload16(Wt + (size_t)(n0 + row) * kD + k0 + ((c ^ ((row >> 1) & 3)) * 8),
            Bs + (wid * 64) * 8);
  };

  const int xorv = (l16 >> 1) & 3;
  f32x4v acc[4][NJ] = {};

  // prologue: fill buffer 0
  stageA(0, smem);
  stageB(0, smem + 2 * ASZ);
  __syncthreads();

  constexpr int NT = kD / 32;
  for (int t = 0; t < NT; ++t) {
    const int c = t & 1;
    bf16* Asc = smem + c * ASZ;
    bf16* Bsc = smem + 2 * ASZ + c * BSZ;
    if (t + 1 < NT) {  // issue next tile's loads before compute (T14)
      stageA((t + 1) * 32, smem + (c ^ 1) * ASZ);
      stageB((t + 1) * 32, smem + 2 * ASZ + (c ^ 1) * BSZ);
    }
    bf16x8v af[4], bfr[NJ];
#pragma unroll
    for (int i = 0; i < 4; ++i) {
      int rowA = wr * 64 + i * 16 + l16;
      af[i] = *(const bf16x8v*)(Asc + rowA * 32 + ((g4 ^ xorv) * 8));
    }
#pragma unroll
    for (int j = 0; j < NJ; ++j) {
      int rowB = wc * WN + j * 16 + l16;
      bfr[j] = *(const bf16x8v*)(Bsc + rowB * 32 + ((g4 ^ xorv) * 8));
    }
#pragma unroll
    for (int i = 0; i < 4; ++i)
#pragma unroll
      for (int j = 0; j < NJ; ++j)
        acc[i][j] = MFMA16(af[i], bfr[j], acc[i][j]);
    __syncthreads();
  }

  // ---- epilogue via per-wave LDS bounce (vectorized stores) ----
  float* bws = (float*)smem + wid * 1152;  // 4608 B per wave
  const int bb = m0 >> 11;
  const int h = n0 >> 6;  // BN=64: one head per n-block

  if (g.omode == 1) {  // bf16 [b][h][s][dh]
    float bj[NJ];
#pragma unroll
    for (int j = 0; j < NJ; ++j) bj[j] = g.bias[n0 + wc * WN + j * 16 + l16];
#pragma unroll
    for (int i = 0; i < 4; ++i) {
#pragma unroll
      for (int j = 0; j < NJ; ++j)
#pragma unroll
        for (int r = 0; r < 4; ++r)
          bws[(g4 * 4 + r) * 36 + j * 16 + l16] = (acc[i][j][r] + bj[j]) * g.scale;
      LGKM0();
#pragma unroll
      for (int cc = 0; cc < 2; ++cc) {
        int id = cc * 64 + lane;
        int row = id >> 3, ch = id & 7;  // 16 rows x 8 chunks of 4
        f32x4v v = *(const f32x4v*)(bws + row * 36 + ch * 4);
        bf16x4v ov = {(bf16)v.x, (bf16)v.y, (bf16)v.z, (bf16)v.w};
        int srow = (m0 + wr * 64 + i * 16 + row) & (kS - 1);
        *(bf16x4v*)((bf16*)g.out +
                    ((size_t)(bb * kH + h) * kS + srow) * kDH + wc * 32 + ch * 4) = ov;
      }
      LGKM0();
    }
  } else if (g.omode == 2) {  // bf16 [b][h][dh][s]  (transposed bounce)
#pragma unroll
    for (int j = 0; j < NJ; ++j) {
      float bj = g.bias[n0 + wc * WN + j * 16 + l16];
#pragma unroll
      for (int i = 0; i < 4; ++i)
#pragma unroll
        for (int r = 0; r < 4; ++r)
          bws[l16 * 72 + i * 16 + g4 * 4 + r] = acc[i][j][r] + bj;
      LGKM0();
#pragma unroll
      for (int cc = 0; cc < 4; ++cc) {
        int id = cc * 64 + lane;
        int row = id >> 4, c = id & 15;  // 16 dh-rows x 16 chunks of 4
        f32x4v v = *(const f32x4v*)(bws + row * 72 + c * 4);
        bf16x4v ov = {(bf16)v.x, (bf16)v.y, (bf16)v.z, (bf16)v.w};
        int dh = wc * 32 + j * 16 + row;
        int sg = (m0 + wr * 64 + c * 4) & (kS - 1);
        *(bf16x4v*)((bf16*)g.out + ((size_t)(bb * kH + h) * kDH + dh) * kS + sg) = ov;
      }
      LGKM0();
    }
  } else {  // fp32 [M][N]
    float bj[NJ];
#pragma unroll
    for (int j = 0; j < NJ; ++j) bj[j] = g.bias[n0 + wc * WN + j * 16 + l16];
#pragma unroll
    for (int i = 0; i < 4; ++i) {
#pragma unroll
      for (int j = 0; j < NJ; ++j)
#pragma unroll
        for (int r = 0; r < 4; ++r)
          bws[(g4 * 4 + r) * 36 + j * 16 + l16] = acc[i][j][r] + bj[j];
      LGKM0();
#pragma unroll
      for (int cc = 0; cc < 2; ++cc) {
        int id = cc * 64 + lane;
        int row = id >> 3, ch = id & 7;
        f32x4v v = *(const f32x4v*)(bws + row * 36 + ch * 4);
        int srow = m0 + wr * 64 + i * 16 + row;
        *(f32x4v*)((float*)g.out + (size_t)srow * kD + n0 + wc * 32 + ch * 4) = v;
      }
      LGKM0();
    }
  }
}

// ---- causal flash attention (v3, measured 53.5 us: KVBLK=64) --------------
// Block = 128 q-rows = 4 waves x 32. K [64kv][64k] + V^T [64dh][64kv] in LDS
// (32 KB dbuf), XOR-swizzled via pre-swizzled global source. Swapped MFMA32
// (S^T = K x Q, O^T = V^T x P^T), in-register softmax via permlane32_swap +
// cvt_pk (T12). Grid (bh=32, qt=16).
__global__ void __launch_bounds__(256) attn_kernel(
    const bf16* __restrict__ Qp, const bf16* __restrict__ Kp,
    const bf16* __restrict__ Vt, bf16* __restrict__ ctx) {
  __shared__ bf16 lds[16384];  // buf0: K@0,V@4096; buf1: K@8192,V@12288
  const int tid = threadIdx.x;
  const int wid = tid >> 6, lane = tid & 63;
  const int l32 = lane & 31, hi = lane >> 5;
  const int bh = blockIdx.x;
  const int qt = blockIdx.y;
  const int q0 = qt * 128;
  const int qw = q0 + wid * 32;
  const bf16* Qh = Qp + (size_t)bh * kS * kDH;
  const bf16* Kh = Kp + (size_t)bh * kS * kDH;
  const bf16* Vh = Vt + (size_t)bh * kDH * kS;

  // Q B-fragments (swapped QK): col q = l32, k = kw*16 + hi*8 + j
  bf16x8v qf[4];
#pragma unroll
  for (int kw = 0; kw < 4; ++kw)
    qf[kw] = *(const bf16x8v*)(Qh + (size_t)(qw + l32) * kDH + kw * 16 + hi * 8);

  f32x16v oacc[2] = {};            // O^T: col q=l32, row dh=crow(r,hi)+32*s
  float mreg = -1e30f, lsum = 0.f; // per-lane (q = qw+l32) softmax state
  const int q_lane = qw + l32;

  const int nt = (q0 >> 6) + 2;    // block kv-tile count (uniform barriers)
  const int ntw = (qw >> 6) + 1;   // wave live-tile count

  const int srow = lane >> 3, schk = lane & 7;
  auto stage = [&](int buf, int k0) {
    bf16* kd = &lds[buf * 8192];
    bf16* vd = kd + 4096;
#pragma unroll
    for (int i = 0; i < 2; ++i) {
      int r = wid * 16 + i * 8 + srow;
      int c = schk ^ (r & 7);
      gload16(Kh + (size_t)(k0 + r) * kDH + c * 8, kd + (wid * 2 + i) * 512);
      gload16(Vh + (size_t)r * kS + k0 + c * 8, vd + (wid * 2 + i) * 512);
    }
  };

  stage(0, 0);
  __syncthreads();
  int cur = 0;
  for (int t = 0; t < nt; ++t) {
    const int k0 = t * 64;
    if (t + 1 < nt) stage(cur ^ 1, k0 + 64);
    if (t < ntw) {
      const bf16* kb = &lds[cur * 8192];
      const bf16* vb = kb + 4096;
      // S^T[kv][q] in two 32-kv subtiles, K-accumulated over 4 k-windows
      f32x16v st[2] = {};
#pragma unroll
      for (int sub = 0; sub < 2; ++sub) {
        int row = sub * 32 + l32;
        const bf16* krow = kb + row * 64;
        int rx = row & 7;
#pragma unroll
        for (int kw = 0; kw < 4; ++kw) {
          int cw = kw * 2 + hi;
          bf16x8v af = *(const bf16x8v*)(krow + ((cw ^ rx) * 8));
          st[sub] = MFMA32(af, qf[kw], st[sub]);
        }
      }
      // causal mask: kv = k0 + sub*32 + (r&3)+8*(r>>2)+4*hi
      if (k0 + 63 > qw) {
#pragma unroll
        for (int sub = 0; sub < 2; ++sub)
#pragma unroll
          for (int r = 0; r < 16; ++r) {
            int kv = k0 + sub * 32 + (r & 3) + 8 * (r >> 2) + 4 * hi;
            if (kv > q_lane) st[sub][r] = -1e30f;
          }
      }
      // in-lane max over 32 + cross-half via permlane32_swap (VALU, no LDS)
      float rm = st[0][0];
#pragma unroll
      for (int sub = 0; sub < 2; ++sub)
#pragma unroll
        for (int r = 0; r < 16; ++r) rm = fmaxf(rm, st[sub][r]);
      {
        uint32x2v sw = __builtin_amdgcn_permlane32_swap(
            __float_as_uint(rm), __float_as_uint(rm), false, false);
        float partner = __uint_as_float(hi ? sw.x : sw.y);
        rm = fmaxf(rm, partner);
      }
      float mn = fmaxf(mreg, rm);
      float al = fexp2(mreg - mn);
      mreg = mn;
      float rs = 0.f;
#pragma unroll
      for (int sub = 0; sub < 2; ++sub)
#pragma unroll
        for (int r = 0; r < 16; ++r) {
          st[sub][r] = fexp2(st[sub][r] - mn);
          rs += st[sub][r];
        }
      {
        uint32x2v sw = __builtin_amdgcn_permlane32_swap(
            __float_as_uint(rs), __float_as_uint(rs), false, false);
        rs += __uint_as_float(hi ? sw.x : sw.y);
      }
      lsum = lsum * al + rs;
#pragma unroll
      for (int s = 0; s < 2; ++s)
#pragma unroll
        for (int r = 0; r < 16; ++r) oacc[s][r] *= al;

      // P^T -> bf16 B-fragments: cvt_pk consecutive-kv pairs, then
      // swap(w[4f],w[4f+2]) / swap(w[4f+1],w[4f+3]) fills k-window f (T12).
      unsigned int w[16];
#pragma unroll
      for (int sub = 0; sub < 2; ++sub)
#pragma unroll
        for (int i = 0; i < 8; ++i) {
          union { bf16x2v h; unsigned int u; } cv;
          cv.h = bf16x2v{(bf16)st[sub][2 * i], (bf16)st[sub][2 * i + 1]};
          w[sub * 8 + i] = cv.u;
        }
      bf16x8v pb[4];
#pragma unroll
      for (int f = 0; f < 4; ++f) {
        uint32x2v r0 = __builtin_amdgcn_permlane32_swap(w[4 * f], w[4 * f + 2], false, false);
        uint32x2v r1 = __builtin_amdgcn_permlane32_swap(w[4 * f + 1], w[4 * f + 3], false, false);
        union { unsigned int u[4]; bf16x8v h; } fu;
        fu.u[0] = r0.x; fu.u[1] = r1.x; fu.u[2] = r0.y; fu.u[3] = r1.y;
        pb[f] = fu.h;
      }
      // PV swapped: O^T += V^T-frag x P^T-frag per kv-window f, dh-sub s
#pragma unroll
      for (int f = 0; f < 4; ++f) {
        int cw = f * 2 + hi;
#pragma unroll
        for (int s = 0; s < 2; ++s) {
          int row = s * 32 + l32;
          bf16x8v vf = *(const bf16x8v*)(vb + row * 64 + ((cw ^ (row & 7)) * 8));
          oacc[s] = MFMA32(vf, pb[f], oacc[s]);
        }
      }
    }
    __syncthreads();
    cur ^= 1;
  }
  // epilogue: lane writes its q-row (l32), dh = (r&3)+8*(r>>2)+4*hi+32*s
  float inv = 1.0f / lsum;
  const int b = bh >> 4, h = bh & 15;
  bf16* crow = ctx + (size_t)(b * kS + qw + l32) * kD + h * 64;
#pragma unroll
  for (int s = 0; s < 2; ++s)
#pragma unroll
    for (int rq = 0; rq < 4; ++rq) {
      union { bf16x4v h; uint32x2v u; } pk;
      pk.h = bf16x4v{(bf16)(oacc[s][rq * 4 + 0] * inv), (bf16)(oacc[s][rq * 4 + 1] * inv),
                     (bf16)(oacc[s][rq * 4 + 2] * inv), (bf16)(oacc[s][rq * 4 + 3] * inv)};
      *(uint32x2v*)(crow + 8 * rq + 4 * hi + 32 * s) = pk.u;
    }
}

// ---------------------------------------------------------------------------
extern "C" void kernel_launch(void* const* d_in, const int* in_sizes, int n_in,
                              void* d_out, int out_size, void* d_ws, size_t ws_size,
                              hipStream_t stream) {
  (void)in_sizes; (void)n_in; (void)out_size; (void)ws_size;
  const float* q  = (const float*)d_in[0];
  const float* k  = (const float*)d_in[1];
  const float* v  = (const float*)d_in[2];
  // d_in[3] = causal mask, structure hardcoded
  const float* Wq = (const float*)d_in[4];
  const float* bq = (const float*)d_in[5];
  const float* Wk = (const float*)d_in[6];
  const float* bk = (const float*)d_in[7];
  const float* Wv = (const float*)d_in[8];
  const float* bv = (const float*)d_in[9];
  const float* Wo = (const float*)d_in[10];
  const float* bo = (const float*)d_in[11];

  char* p = (char*)d_ws;
  auto carve = [&](size_t bytes) {
    char* r = p;
    p += (bytes + 255) & ~(size_t)255;
    return r;
  };
  const size_t XB = (size_t)kM * kD * sizeof(bf16);  // 8 MB
  const size_t WB = (size_t)kD * kD * sizeof(bf16);  // 2 MB
  bf16* Xq  = (bf16*)carve(XB);
  bf16* Xk  = (bf16*)carve(XB);
  bf16* Xv  = (bf16*)carve(XB);
  bf16* Wtq = (bf16*)carve(WB);
  bf16* Wtk = (bf16*)carve(WB);
  bf16* Wtv = (bf16*)carve(WB);
  bf16* Wto = (bf16*)carve(WB);
  bf16* Qp  = (bf16*)carve(XB);  // [b][h][s][dh], pre-scaled (log2 domain)
  bf16* Kp  = (bf16*)carve(XB);  // [b][h][s][dh]
  bf16* Vt  = (bf16*)carve(XB);  // [b][h][dh][s]
  bf16* Ctx = (bf16*)carve(XB);  // [b*s][d]

  cvt_x_kernel<<<dim3(kM * kD / 1024), 256, 0, stream>>>(q, k, v, Xq, Xk, Xv);
  cvt_w_kernel<<<dim3(32, 32, 4), dim3(32, 8, 1), 0, stream>>>(Wq, Wk, Wv, Wo,
                                                               Wtq, Wtk, Wtv, Wto);
  // fold 1/sqrt(DH) * log2(e) into Q (softmax runs in log2 domain)
  GemmArgs aq{Xq, Wtq, bq, Qp, 0.125f * 1.44269504f, 1};
  GemmArgs ak{Xk, Wtk, bk, Kp, 1.0f, 1};
  GemmArgs av{Xv, Wtv, bv, Vt, 1.0f, 2};
  gemm_kernel<<<dim3(32, 16, 3), 256, 0, stream>>>(aq, ak, av);
  attn_kernel<<<dim3(32, 16), 256, 0, stream>>>(Qp, Kp, Vt, Ctx);
  GemmArgs ao{Ctx, Wto, bo, d_out, 1.0f, 0};
  gemm_kernel<<<dim3(32, 16, 1), 256, 0, stream>>>(ao, ao, ao);
}

// Round 10
// 236.171 us; speedup vs baseline: 1.3112x; 1.0148x over previous
//
#include <hip/hip_runtime.h>
#include <hip/hip_bf16.h>
#include <stdint.h>

// ---------------------------------------------------------------------------
// Fused MHA: cvt(fp32->bf16) -> QKV GEMMs (bf16 MFMA, 128x64 tiles, dbuf
// gload_lds pipeline) -> causal flash attention (v3 + balanced qt pairing +
// defer-max) -> output GEMM (64x64 tiles, 4 blocks/CU).
// ---------------------------------------------------------------------------

typedef __bf16 bf16;
typedef __bf16 bf16x2v __attribute__((ext_vector_type(2)));
typedef __bf16 bf16x4v __attribute__((ext_vector_type(4)));
typedef __bf16 bf16x8v __attribute__((ext_vector_type(8)));
typedef float  f32x4v  __attribute__((ext_vector_type(4)));
typedef float  f32x16v __attribute__((ext_vector_type(16)));
typedef unsigned int uint32x2v __attribute__((ext_vector_type(2)));

#define MFMA32(a, b, c) __builtin_amdgcn_mfma_f32_32x32x16_bf16((a), (b), (c), 0, 0, 0)
#define MFMA16(a, b, c) __builtin_amdgcn_mfma_f32_16x16x32_bf16((a), (b), (c), 0, 0, 0)
#define LGKM0() asm volatile("s_waitcnt lgkmcnt(0)" ::: "memory")

static constexpr int kS = 2048, kD = 1024, kH = 16, kDH = 64, kM = 4096;

__device__ __forceinline__ void gload16(const void* g, void* lds) {
  __builtin_amdgcn_global_load_lds((const __attribute__((address_space(1))) void*)g,
                                   (__attribute__((address_space(3))) void*)lds, 16, 0, 0);
}

__device__ __forceinline__ float fexp2(float x) {
#if __has_builtin(__builtin_amdgcn_exp2f)
  return __builtin_amdgcn_exp2f(x);
#else
  return exp2f(x);
#endif
}

// ---- convert q,k,v fp32 -> bf16 (vectorized, G13) -------------------------
__global__ void __launch_bounds__(256) cvt_x_kernel(
    const float* __restrict__ q, const float* __restrict__ k, const float* __restrict__ v,
    bf16* __restrict__ xq, bf16* __restrict__ xk, bf16* __restrict__ xv) {
  int i = (blockIdx.x * 256 + threadIdx.x) * 4;
  float4 a = *(const float4*)(q + i);
  float4 b = *(const float4*)(k + i);
  float4 c = *(const float4*)(v + i);
  bf16x4v oa = {(bf16)a.x, (bf16)a.y, (bf16)a.z, (bf16)a.w};
  bf16x4v ob = {(bf16)b.x, (bf16)b.y, (bf16)b.z, (bf16)b.w};
  bf16x4v oc = {(bf16)c.x, (bf16)c.y, (bf16)c.z, (bf16)c.w};
  *(bf16x4v*)(xq + i) = oa;
  *(bf16x4v*)(xk + i) = ob;
  *(bf16x4v*)(xv + i) = oc;
}

// ---- transpose + convert weights: Wt[n][k] = W[k][n] ----------------------
__global__ void __launch_bounds__(256) cvt_w_kernel(
    const float* __restrict__ w0, const float* __restrict__ w1,
    const float* __restrict__ w2, const float* __restrict__ w3,
    bf16* __restrict__ o0, bf16* __restrict__ o1, bf16* __restrict__ o2, bf16* __restrict__ o3) {
  const float* w = blockIdx.z == 0 ? w0 : blockIdx.z == 1 ? w1 : blockIdx.z == 2 ? w2 : w3;
  bf16* o       = blockIdx.z == 0 ? o0 : blockIdx.z == 1 ? o1 : blockIdx.z == 2 ? o2 : o3;
  __shared__ float t[32][33];
  int tx = threadIdx.x, ty = threadIdx.y;
  int k0 = blockIdx.x * 32, n0 = blockIdx.y * 32;
#pragma unroll
  for (int j = 0; j < 4; ++j)
    t[ty + j * 8][tx] = w[(size_t)(k0 + ty + j * 8) * kD + n0 + tx];
  __syncthreads();
#pragma unroll
  for (int j = 0; j < 4; ++j)
    o[(size_t)(n0 + ty + j * 8) * kD + k0 + tx] = (bf16)t[tx][ty + j * 8];
}

// ---- GEMM: C[BM x 64] tiles, A [M][1024] bf16, Wt [N][K] bf16. ------------
// Double-buffered gload_lds pipeline (prefetch next before compute current).
// BM=128 for QKV (5 blocks/CU), BM=64 for O-gemm (grid 1024 -> 4 blocks/CU).
struct GemmArgs {
  const bf16* A;
  const bf16* Wt;
  const float* bias;
  void* out;
  float scale;
  int omode;  // 0: f32 [M][N]; 1: bf16 [b][h][s][dh]; 2: bf16 [b][h][dh][s]
};            // omode 1/2 valid only for BM=128 instances

template <int BM>
__global__ void __launch_bounds__(256) gemm_kernel(GemmArgs ga, GemmArgs gb, GemmArgs gc) {
  GemmArgs g = blockIdx.z == 0 ? ga : blockIdx.z == 1 ? gb : gc;
  constexpr int BN = 64, WN = 32, NJ = 2;
  constexpr int WM = BM / 2, MI = WM / 16;
  constexpr int ASZ = BM * 32;
  constexpr int BSZ = BN * 32;
  __shared__ __align__(16) bf16 smem[2 * ASZ + 2 * BSZ];
  const int tid = threadIdx.x, wid = tid >> 6, lane = tid & 63;
  const int g4 = lane >> 4, l16 = lane & 15;
  const int m0 = blockIdx.x * BM, n0 = blockIdx.y * BN;
  const int wr = wid >> 1, wc = wid & 1;
  const bf16* Wt = g.Wt;

  auto stageA = [&](int k0, bf16* As) {
#pragma unroll
    for (int i = 0; i < BM / 64; ++i) {
      int id = i * 256 + tid;
      int row = id >> 2, c = id & 3;
      gload16(g.A + (size_t)(m0 + row) * kD + k0 + ((c ^ ((row >> 1) & 3)) * 8),
              As + (i * 256 + wid * 64) * 8);
    }
  };
  auto stageB = [&](int k0, bf16* Bs) {
    int row = tid >> 2, c = tid & 3;
    gload16(Wt + (size_t)(n0 + row) * kD + k0 + ((c ^ ((row >> 1) & 3)) * 8),
            Bs + (wid * 64) * 8);
  };

  const int xorv = (l16 >> 1) & 3;
  f32x4v acc[MI][NJ] = {};

  stageA(0, smem);
  stageB(0, smem + 2 * ASZ);
  __syncthreads();

  constexpr int NT = kD / 32;
  for (int t = 0; t < NT; ++t) {
    const int c = t & 1;
    bf16* Asc = smem + c * ASZ;
    bf16* Bsc = smem + 2 * ASZ + c * BSZ;
    if (t + 1 < NT) {  // issue next tile's loads before compute (T14)
      stageA((t + 1) * 32, smem + (c ^ 1) * ASZ);
      stageB((t + 1) * 32, smem + 2 * ASZ + (c ^ 1) * BSZ);
    }
    bf16x8v af[MI], bfr[NJ];
#pragma unroll
    for (int i = 0; i < MI; ++i) {
      int rowA = wr * WM + i * 16 + l16;
      af[i] = *(const bf16x8v*)(Asc + rowA * 32 + ((g4 ^ xorv) * 8));
    }
#pragma unroll
    for (int j = 0; j < NJ; ++j) {
      int rowB = wc * WN + j * 16 + l16;
      bfr[j] = *(const bf16x8v*)(Bsc + rowB * 32 + ((g4 ^ xorv) * 8));
    }
#pragma unroll
    for (int i = 0; i < MI; ++i)
#pragma unroll
      for (int j = 0; j < NJ; ++j)
        acc[i][j] = MFMA16(af[i], bfr[j], acc[i][j]);
    __syncthreads();
  }

  // ---- epilogue via per-wave LDS bounce (vectorized stores) ----
  float* bws = (float*)smem + wid * 1152;  // 4608 B per wave
  const int bb = m0 >> 11;
  const int h = n0 >> 6;  // BN=64: one head per n-block

  if (g.omode == 1) {  // bf16 [b][h][s][dh]  (BM=128 only)
    float bj[NJ];
#pragma unroll
    for (int j = 0; j < NJ; ++j) bj[j] = g.bias[n0 + wc * WN + j * 16 + l16];
#pragma unroll
    for (int i = 0; i < MI; ++i) {
#pragma unroll
      for (int j = 0; j < NJ; ++j)
#pragma unroll
        for (int r = 0; r < 4; ++r)
          bws[(g4 * 4 + r) * 36 + j * 16 + l16] = (acc[i][j][r] + bj[j]) * g.scale;
      LGKM0();
#pragma unroll
      for (int cc = 0; cc < 2; ++cc) {
        int id = cc * 64 + lane;
        int row = id >> 3, ch = id & 7;  // 16 rows x 8 chunks of 4
        f32x4v v = *(const f32x4v*)(bws + row * 36 + ch * 4);
        bf16x4v ov = {(bf16)v.x, (bf16)v.y, (bf16)v.z, (bf16)v.w};
        int srow = (m0 + wr * WM + i * 16 + row) & (kS - 1);
        *(bf16x4v*)((bf16*)g.out +
                    ((size_t)(bb * kH + h) * kS + srow) * kDH + wc * 32 + ch * 4) = ov;
      }
      LGKM0();
    }
  } else if (g.omode == 2) {  // bf16 [b][h][dh][s]  (BM=128 only)
#pragma unroll
    for (int j = 0; j < NJ; ++j) {
      float bj = g.bias[n0 + wc * WN + j * 16 + l16];
#pragma unroll
      for (int i = 0; i < MI; ++i)
#pragma unroll
        for (int r = 0; r < 4; ++r)
          bws[l16 * 72 + i * 16 + g4 * 4 + r] = acc[i][j][r] + bj;
      LGKM0();
#pragma unroll
      for (int cc = 0; cc < 4; ++cc) {
        int id = cc * 64 + lane;
        int row = id >> 4, c = id & 15;  // 16 dh-rows x 16 chunks of 4
        f32x4v v = *(const f32x4v*)(bws + row * 72 + c * 4);
        bf16x4v ov = {(bf16)v.x, (bf16)v.y, (bf16)v.z, (bf16)v.w};
        int dh = wc * 32 + j * 16 + row;
        int sg = (m0 + wr * WM + c * 4) & (kS - 1);
        *(bf16x4v*)((bf16*)g.out + ((size_t)(bb * kH + h) * kDH + dh) * kS + sg) = ov;
      }
      LGKM0();
    }
  } else {  // fp32 [M][N]
    float bj[NJ];
#pragma unroll
    for (int j = 0; j < NJ; ++j) bj[j] = g.bias[n0 + wc * WN + j * 16 + l16];
#pragma unroll
    for (int i = 0; i < MI; ++i) {
#pragma unroll
      for (int j = 0; j < NJ; ++j)
#pragma unroll
        for (int r = 0; r < 4; ++r)
          bws[(g4 * 4 + r) * 36 + j * 16 + l16] = acc[i][j][r] + bj[j];
      LGKM0();
#pragma unroll
      for (int cc = 0; cc < 2; ++cc) {
        int id = cc * 64 + lane;
        int row = id >> 3, ch = id & 7;
        f32x4v v = *(const f32x4v*)(bws + row * 36 + ch * 4);
        int srow = m0 + wr * WM + i * 16 + row;
        *(f32x4v*)((float*)g.out + (size_t)srow * kD + n0 + wc * 32 + ch * 4) = v;
      }
      LGKM0();
    }
  }
}

// ---- causal flash attention (v5 = v3 + balanced pairing + defer-max) ------
// 1D grid 512: bid<256 -> qt=bid>>5; else qt=15-((bid-256)>>5). Blocks b and
// b+256 co-locate on a CU (8 XCD x 32 CU round-robin) -> per-CU work
// (qt+1)+(16-qt) = 17 kv-tiles, exactly balanced (was 10..24).
__global__ void __launch_bounds__(256) attn_kernel(
    const bf16* __restrict__ Qp, const bf16* __restrict__ Kp,
    const bf16* __restrict__ Vt, bf16* __restrict__ ctx) {
  __shared__ bf16 lds[16384];  // buf0: K@0,V@4096; buf1: K@8192,V@12288
  const int tid = threadIdx.x;
  const int wid = tid >> 6, lane = tid & 63;
  const int l32 = lane & 31, hi = lane >> 5;
  const int bid = blockIdx.x;
  int qt, bh;
  if (bid < 256) { qt = bid >> 5; bh = bid & 31; }
  else           { qt = 15 - ((bid - 256) >> 5); bh = (bid - 256) & 31; }
  const int q0 = qt * 128;
  const int qw = q0 + wid * 32;
  const bf16* Qh = Qp + (size_t)bh * kS * kDH;
  const bf16* Kh = Kp + (size_t)bh * kS * kDH;
  const bf16* Vh = Vt + (size_t)bh * kDH * kS;

  // Q B-fragments (swapped QK): col q = l32, k = kw*16 + hi*8 + j
  bf16x8v qf[4];
#pragma unroll
  for (int kw = 0; kw < 4; ++kw)
    qf[kw] = *(const bf16x8v*)(Qh + (size_t)(qw + l32) * kDH + kw * 16 + hi * 8);

  f32x16v oacc[2] = {};            // O^T: col q=l32, row dh=crow(r,hi)+32*s
  float mreg = -1e30f, lsum = 0.f; // per-lane (q = qw+l32) softmax state
  const int q_lane = qw + l32;

  const int nt = (q0 >> 6) + 2;    // block kv-tile count (uniform barriers)
  const int ntw = (qw >> 6) + 1;   // wave live-tile count

  const int srow = lane >> 3, schk = lane & 7;
  auto stage = [&](int buf, int k0) {
    bf16* kd = &lds[buf * 8192];
    bf16* vd = kd + 4096;
#pragma unroll
    for (int i = 0; i < 2; ++i) {
      int r = wid * 16 + i * 8 + srow;
      int c = schk ^ (r & 7);
      gload16(Kh + (size_t)(k0 + r) * kDH + c * 8, kd + (wid * 2 + i) * 512);
      gload16(Vh + (size_t)r * kS + k0 + c * 8, vd + (wid * 2 + i) * 512);
    }
  };

  stage(0, 0);
  __syncthreads();
  int cur = 0;
  for (int t = 0; t < nt; ++t) {
    const int k0 = t * 64;
    if (t + 1 < nt) stage(cur ^ 1, k0 + 64);
    if (t < ntw) {
      const bf16* kb = &lds[cur * 8192];
      const bf16* vb = kb + 4096;
      // S^T[kv][q] in two 32-kv subtiles, K-accumulated over 4 k-windows
      f32x16v st[2] = {};
#pragma unroll
      for (int sub = 0; sub < 2; ++sub) {
        int row = sub * 32 + l32;
        const bf16* krow = kb + row * 64;
        int rx = row & 7;
#pragma unroll
        for (int kw = 0; kw < 4; ++kw) {
          int cw = kw * 2 + hi;
          bf16x8v af = *(const bf16x8v*)(krow + ((cw ^ rx) * 8));
          st[sub] = MFMA32(af, qf[kw], st[sub]);
        }
      }
      // causal mask: kv = k0 + sub*32 + (r&3)+8*(r>>2)+4*hi
      if (k0 + 63 > qw) {
#pragma unroll
        for (int sub = 0; sub < 2; ++sub)
#pragma unroll
          for (int r = 0; r < 16; ++r) {
            int kv = k0 + sub * 32 + (r & 3) + 8 * (r >> 2) + 4 * hi;
            if (kv > q_lane) st[sub][r] = -1e30f;
          }
      }
      // in-lane max over 32 + cross-half via permlane32_swap (VALU, no LDS)
      float rm = st[0][0];
#pragma unroll
      for (int sub = 0; sub < 2; ++sub)
#pragma unroll
        for (int r = 0; r < 16; ++r) rm = fmaxf(rm, st[sub][r]);
      {
        uint32x2v sw = __builtin_amdgcn_permlane32_swap(
            __float_as_uint(rm), __float_as_uint(rm), false, false);
        float partner = __uint_as_float(hi ? sw.x : sw.y);
        rm = fmaxf(rm, partner);
      }
      // defer-max (T13): rescale only when the running max grows
      if (!__all(rm <= mreg)) {
        float mn = fmaxf(mreg, rm);
        float al = fexp2(mreg - mn);
        mreg = mn;
        lsum *= al;
#pragma unroll
        for (int s = 0; s < 2; ++s)
#pragma unroll
          for (int r = 0; r < 16; ++r) oacc[s][r] *= al;
      }
      float rs = 0.f;
#pragma unroll
      for (int sub = 0; sub < 2; ++sub)
#pragma unroll
        for (int r = 0; r < 16; ++r) {
          st[sub][r] = fexp2(st[sub][r] - mreg);
          rs += st[sub][r];
        }
      {
        uint32x2v sw = __builtin_amdgcn_permlane32_swap(
            __float_as_uint(rs), __float_as_uint(rs), false, false);
        rs += __uint_as_float(hi ? sw.x : sw.y);
      }
      lsum += rs;

      // P^T -> bf16 B-fragments: cvt_pk consecutive-kv pairs, then
      // swap(w[4f],w[4f+2]) / swap(w[4f+1],w[4f+3]) fills k-window f (T12).
      unsigned int w[16];
#pragma unroll
      for (int sub = 0; sub < 2; ++sub)
#pragma unroll
        for (int i = 0; i < 8; ++i) {
          union { bf16x2v h; unsigned int u; } cv;
          cv.h = bf16x2v{(bf16)st[sub][2 * i], (bf16)st[sub][2 * i + 1]};
          w[sub * 8 + i] = cv.u;
        }
      bf16x8v pb[4];
#pragma unroll
      for (int f = 0; f < 4; ++f) {
        uint32x2v r0 = __builtin_amdgcn_permlane32_swap(w[4 * f], w[4 * f + 2], false, false);
        uint32x2v r1 = __builtin_amdgcn_permlane32_swap(w[4 * f + 1], w[4 * f + 3], false, false);
        union { unsigned int u[4]; bf16x8v h; } fu;
        fu.u[0] = r0.x; fu.u[1] = r1.x; fu.u[2] = r0.y; fu.u[3] = r1.y;
        pb[f] = fu.h;
      }
      // PV swapped: O^T += V^T-frag x P^T-frag per kv-window f, dh-sub s
#pragma unroll
      for (int f = 0; f < 4; ++f) {
        int cw = f * 2 + hi;
#pragma unroll
        for (int s = 0; s < 2; ++s) {
          int row = s * 32 + l32;
          bf16x8v vf = *(const bf16x8v*)(vb + row * 64 + ((cw ^ (row & 7)) * 8));
          oacc[s] = MFMA32(vf, pb[f], oacc[s]);
        }
      }
    }
    __syncthreads();
    cur ^= 1;
  }
  // epilogue: lane writes its q-row (l32), dh = (r&3)+8*(r>>2)+4*hi+32*s
  float inv = 1.0f / lsum;
  const int b = bh >> 4, h = bh & 15;
  bf16* crow = ctx + (size_t)(b * kS + qw + l32) * kD + h * 64;
#pragma unroll
  for (int s = 0; s < 2; ++s)
#pragma unroll
    for (int rq = 0; rq < 4; ++rq) {
      union { bf16x4v h; uint32x2v u; } pk;
      pk.h = bf16x4v{(bf16)(oacc[s][rq * 4 + 0] * inv), (bf16)(oacc[s][rq * 4 + 1] * inv),
                     (bf16)(oacc[s][rq * 4 + 2] * inv), (bf16)(oacc[s][rq * 4 + 3] * inv)};
      *(uint32x2v*)(crow + 8 * rq + 4 * hi + 32 * s) = pk.u;
    }
}

// ---------------------------------------------------------------------------
extern "C" void kernel_launch(void* const* d_in, const int* in_sizes, int n_in,
                              void* d_out, int out_size, void* d_ws, size_t ws_size,
                              hipStream_t stream) {
  (void)in_sizes; (void)n_in; (void)out_size; (void)ws_size;
  const float* q  = (const float*)d_in[0];
  const float* k  = (const float*)d_in[1];
  const float* v  = (const float*)d_in[2];
  // d_in[3] = causal mask, structure hardcoded
  const float* Wq = (const float*)d_in[4];
  const float* bq = (const float*)d_in[5];
  const float* Wk = (const float*)d_in[6];
  const float* bk = (const float*)d_in[7];
  const float* Wv = (const float*)d_in[8];
  const float* bv = (const float*)d_in[9];
  const float* Wo = (const float*)d_in[10];
  const float* bo = (const float*)d_in[11];

  char* p = (char*)d_ws;
  auto carve = [&](size_t bytes) {
    char* r = p;
    p += (bytes + 255) & ~(size_t)255;
    return r;
  };
  const size_t XB = (size_t)kM * kD * sizeof(bf16);  // 8 MB
  const size_t WB = (size_t)kD * kD * sizeof(bf16);  // 2 MB
  bf16* Xq  = (bf16*)carve(XB);
  bf16* Xk  = (bf16*)carve(XB);
  bf16* Xv  = (bf16*)carve(XB);
  bf16* Wtq = (bf16*)carve(WB);
  bf16* Wtk = (bf16*)carve(WB);
  bf16* Wtv = (bf16*)carve(WB);
  bf16* Wto = (bf16*)carve(WB);
  bf16* Qp  = (bf16*)carve(XB);  // [b][h][s][dh], pre-scaled (log2 domain)
  bf16* Kp  = (bf16*)carve(XB);  // [b][h][s][dh]
  bf16* Vt  = (bf16*)carve(XB);  // [b][h][dh][s]
  bf16* Ctx = (bf16*)carve(XB);  // [b*s][d]

  cvt_x_kernel<<<dim3(kM * kD / 1024), 256, 0, stream>>>(q, k, v, Xq, Xk, Xv);
  cvt_w_kernel<<<dim3(32, 32, 4), dim3(32, 8, 1), 0, stream>>>(Wq, Wk, Wv, Wo,
                                                               Wtq, Wtk, Wtv, Wto);
  // fold 1/sqrt(DH) * log2(e) into Q (softmax runs in log2 domain)
  GemmArgs aq{Xq, Wtq, bq, Qp, 0.125f * 1.44269504f, 1};
  GemmArgs ak{Xk, Wtk, bk, Kp, 1.0f, 1};
  GemmArgs av{Xv, Wtv, bv, Vt, 1.0f, 2};
  gemm_kernel<128><<<dim3(32, 16, 3), 256, 0, stream>>>(aq, ak, av);
  attn_kernel<<<dim3(512), 256, 0, stream>>>(Qp, Kp, Vt, Ctx);
  GemmArgs ao{Ctx, Wto, bo, d_out, 1.0f, 0};
  gemm_kernel<64><<<dim3(64, 16, 1), 256, 0, stream>>>(ao, ao, ao);
}